// Round 2
// baseline (322.972 us; speedup 1.0000x reference)
//
#include <hip/hip_runtime.h>

#define BB 128
#define SS 512
#define DD 1024
#define START_ID 30522
#define END_ID   30523
#define NPART 64   // d-slices for M partials (16 d each)

__device__ __forceinline__ void f4add(float4& a, const float4 b, float s) {
    a.x += s * b.x; a.y += s * b.y; a.z += s * b.z; a.w += s * b.w;
}

// Kernel A: Mpart[p][j][k] = sum_{d in slice p} W2[j,d] * W1[d,k], 64 slices of 16 d.
// Block 64 computes consts[j] = W2[j,:]·b1 + b2[j].
__global__ void prep_kernel(const float* __restrict__ W1,
                            const float* __restrict__ W2,
                            const float* __restrict__ b1,
                            const float* __restrict__ b2,
                            float* __restrict__ Mpart,
                            float* __restrict__ consts) {
    const int p = blockIdx.x;
    const int t = threadIdx.x;

    if (p < NPART) {
        const int k4 = 4 * t;
        float4 m0 = make_float4(0.f, 0.f, 0.f, 0.f);
        float4 m1 = make_float4(0.f, 0.f, 0.f, 0.f);
        #pragma unroll
        for (int i = 0; i < 16; ++i) {
            const int d = p * 16 + i;
            const float4 w1 = *(const float4*)(W1 + (size_t)d * DD + k4);
            f4add(m0, w1, W2[d]);
            f4add(m1, w1, W2[DD + d]);
        }
        *(float4*)(Mpart + (size_t)p * 2 * DD + k4) = m0;
        *(float4*)(Mpart + (size_t)p * 2 * DD + DD + k4) = m1;
    } else {
        float c0 = 0.f, c1 = 0.f;
        for (int k = t; k < DD; k += 256) {
            const float bv = b1[k];
            c0 += W2[k]      * bv;
            c1 += W2[DD + k] * bv;
        }
        __shared__ float r0[256], r1[256];
        r0[t] = c0; r1[t] = c1;
        __syncthreads();
        for (int off = 128; off >= 1; off >>= 1) {
            if (t < off) { r0[t] += r0[t + off]; r1[t] += r1[t + off]; }
            __syncthreads();
        }
        if (t == 0) {
            consts[0] = r0[0] + b2[0];
            consts[1] = r1[0] + b2[1];
        }
    }
}

// Kernel B: per row — span find, euph in registers, dot with reduced M, write out[b,0:2].
__global__ void row_kernel(const float* __restrict__ inputs,
                           const int* __restrict__ ids,
                           const float* __restrict__ Mpart,
                           const float* __restrict__ consts,
                           float* __restrict__ out) {
    const int b = blockIdx.x;
    const int t = threadIdx.x;

    __shared__ int s_start, s_end;
    for (int s = t; s < SS; s += 256) {
        const int id = ids[b * SS + s];
        if (id == START_ID) s_start = s;   // exactly one per row
        if (id == END_ID)   s_end = s;
    }
    __syncthreads();
    const int st = s_start;
    const int en = s_end;

    // euph fragment for k = 4t..4t+3, kept in registers
    float4 acc = make_float4(0.f, 0.f, 0.f, 0.f);
    const size_t rowbase = (size_t)b * SS * DD + 4 * t;
    for (int s = st + 1; s < en; ++s) {
        const float4 v = *(const float4*)(inputs + rowbase + (size_t)s * DD);
        acc.x += v.x; acc.y += v.y; acc.z += v.z; acc.w += v.w;
    }

    // reduce M partials for this k-fragment (L2-hot, 2 KB/thread)
    float4 M0 = make_float4(0.f, 0.f, 0.f, 0.f);
    float4 M1 = make_float4(0.f, 0.f, 0.f, 0.f);
    const float* mp = Mpart + 4 * t;
    #pragma unroll 8
    for (int p = 0; p < NPART; ++p) {
        const float4 a = *(const float4*)(mp + (size_t)p * 2 * DD);
        const float4 c = *(const float4*)(mp + (size_t)p * 2 * DD + DD);
        M0.x += a.x; M0.y += a.y; M0.z += a.z; M0.w += a.w;
        M1.x += c.x; M1.y += c.y; M1.z += c.z; M1.w += c.w;
    }

    float s0 = acc.x * M0.x + acc.y * M0.y + acc.z * M0.z + acc.w * M0.w;
    float s1 = acc.x * M1.x + acc.y * M1.y + acc.z * M1.z + acc.w * M1.w;

    __shared__ float r0[256], r1[256];
    r0[t] = s0; r1[t] = s1;
    __syncthreads();
    for (int off = 128; off >= 1; off >>= 1) {
        if (t < off) { r0[t] += r0[t + off]; r1[t] += r1[t + off]; }
        __syncthreads();
    }
    if (t == 0) {
        out[2 * b]     = r0[0] + consts[0];
        out[2 * b + 1] = r1[0] + consts[1];
    }
}

extern "C" void kernel_launch(void* const* d_in, const int* in_sizes, int n_in,
                              void* d_out, int out_size, void* d_ws, size_t ws_size,
                              hipStream_t stream) {
    const float* inputs = (const float*)d_in[0];
    const int*   ids    = (const int*)d_in[1];
    const float* W1     = (const float*)d_in[2];
    const float* b1     = (const float*)d_in[3];
    const float* W2     = (const float*)d_in[4];
    const float* b2     = (const float*)d_in[5];
    float* out = (float*)d_out;

    float* Mpart  = (float*)d_ws;                       // 64*2*1024 floats = 512 KiB
    float* consts = Mpart + (size_t)NPART * 2 * DD;     // 2 floats

    prep_kernel<<<NPART + 1, 256, 0, stream>>>(W1, W2, b1, b2, Mpart, consts);
    row_kernel<<<BB, 256, 0, stream>>>(inputs, ids, Mpart, consts, out);
}